// Round 8
// baseline (687.576 us; speedup 1.0000x reference)
//
#include <hip/hip_runtime.h>

#define EPS_C 0.01f
#define NU    128
#define DIN   64
#define COUT  10

typedef float    f32x4 __attribute__((ext_vector_type(4)));
typedef _Float16 f16x4 __attribute__((ext_vector_type(4)));
typedef _Float16 f16x8 __attribute__((ext_vector_type(8)));

#define MFMA32(A, B, C) __builtin_amdgcn_mfma_f32_16x16x32_f16((A), (B), (C), 0, 0, 0)
// LDS-only barrier: x prefetch loads stay in flight (round-7 win).
#define BAR() asm volatile("s_waitcnt lgkmcnt(0)\n\ts_barrier" ::: "memory")

// Transposed recurrence, batch along MFMA n-dim (16 rows/block, 32 blocks).
// 4 waves (256 thr) — h-broadcast LDS traffic scales with wave count, and
// 1 wave/SIMD keeps epilogue issue costs single. Wave w owns m-tiles {2w,2w+1}.
// mfma_f32_16x16x32_f16 layouts (HW-verified):
//   A-op: A[m=lane&15][k=quad*8+j]  B-op: B[k=quad*8+j][n=lane&15]
//   D  : D[row=quad*4+reg][col=lane&15]
// h exchange (D->B shuffle): u=16(2w+mtl)+4q+r, b=lid ->
//   hbuf[w][(2*mtl+(q>>1))*16+lid][(q&1)*4+r]; reads linear ds_read_b128.
__global__ __launch_bounds__(256, 1)
void rnn_core(const float* __restrict__ x,
              const float* __restrict__ E_w, const float* __restrict__ E_b,
              const float* __restrict__ B_p, const float* __restrict__ C_p,
              const float* __restrict__ D_w, const float* __restrict__ D_b,
              float* __restrict__ out, int T)
{
    const int tid  = threadIdx.x;
    const int lane = tid & 63;
    const int w    = tid >> 6;     // wave 0..3
    const int lid  = lane & 15;
    const int q    = lane >> 4;
    const int g    = blockIdx.x;   // batch group (16 rows)

    __shared__ _Float16 xs[2][16 * 2 * 64 * 8];   // 2 x 32 KB, B-frag layout
    __shared__ _Float16 hbuf[2][4][64][8];        // [parity][kt][lane][j] 8 KB
    __shared__ float    hfin[16][NU + 4];

    // ---- one-time weight fragments (wave w: m-tiles 2w, 2w+1) ----
    f16x8 AT[2][4], WT[2][4], EF[2][2];
    f32x4 ebv[2];
    #pragma unroll
    for (int mtl = 0; mtl < 2; ++mtl) {
        const int m = (w * 2 + mtl) * 16 + lid;
        #pragma unroll
        for (int kt = 0; kt < 4; ++kt) {
            f16x8 fa, fw;
            #pragma unroll
            for (int j = 0; j < 8; ++j) {
                const int k  = kt * 32 + q * 8 + j;
                const float dg = (k == m) ? 0.01f : 0.0f;
                fa[j] = (_Float16)(B_p[k * NU + m] - 0.6f * B_p[m * NU + k] - dg);
                fw[j] = (_Float16)(C_p[k * NU + m] - 0.6f * C_p[m * NU + k] - dg);
            }
            AT[mtl][kt] = fa;  WT[mtl][kt] = fw;
        }
        #pragma unroll
        for (int kt = 0; kt < 2; ++kt) {
            f16x8 fe;
            #pragma unroll
            for (int j = 0; j < 8; ++j)
                fe[j] = (_Float16)E_w[m * DIN + kt * 32 + q * 8 + j];
            EF[mtl][kt] = fe;
        }
        #pragma unroll
        for (int r = 0; r < 4; ++r)
            ebv[mtl][r] = E_b[(w * 2 + mtl) * 16 + q * 4 + r];
    }

    // ---- x staging mapping (256 threads, 16 steps/chunk) ----
    const int bb = tid & 15;        // batch row
    const int s  = tid >> 4;        // d-quad: d = 4s..4s+3
    const float* xrow = x + ((size_t)(g * 16 + bb) * T) * DIN + s * 4;
    const int wbyte = (((s >> 3) * 64) + (((s >> 1) & 3) * 16) + bb) * 16 + (s & 1) * 8;

    float4 xg[16];

#define STAGE_WRITE_RANGE(BUF, I0, I1)                                        \
    {                                                                         \
        char* base_ = (char*)&xs[(BUF)][0];                                   \
        _Pragma("unroll")                                                     \
        for (int i2 = (I0); i2 < (I1); ++i2) {                                \
            float4 v_ = xg[i2];                                               \
            f16x4 h4_;                                                        \
            h4_[0] = (_Float16)v_.x; h4_[1] = (_Float16)v_.y;                 \
            h4_[2] = (_Float16)v_.z; h4_[3] = (_Float16)v_.w;                 \
            *(f16x4*)(base_ + i2 * 2048 + wbyte) = h4_;                       \
        }                                                                     \
    }

    // ---- init: zero parity-0 h buffer (4 KB); stage chunk 0 ----
    ((float4*)&hbuf[0][0][0][0])[tid] = (float4){0.f, 0.f, 0.f, 0.f};
    #pragma unroll
    for (int i = 0; i < 16; ++i)
        xg[i] = *(const float4*)(xrow + (size_t)i * DIN);
    STAGE_WRITE_RANGE(0, 0, 16)
    __syncthreads();

    // ---- state init: h = 0, z_cur = z(0) ----
    f32x4 hf[2] = {{0.f, 0.f, 0.f, 0.f}, {0.f, 0.f, 0.f, 0.f}};
    f32x4 zc[2];
    {
        f16x8 x0 = *(const f16x8*)((char*)&xs[0][0] + (0 * 64 + lane) * 16);
        f16x8 x1 = *(const f16x8*)((char*)&xs[0][0] + (1 * 64 + lane) * 16);
        zc[0] = ebv[0];  zc[1] = ebv[1];
        zc[0] = MFMA32(EF[0][0], x0, zc[0]);
        zc[1] = MFMA32(EF[1][0], x0, zc[1]);
        zc[0] = MFMA32(EF[0][1], x1, zc[0]);
        zc[1] = MFMA32(EF[1][1], x1, zc[1]);
    }

    const int nch = T >> 4;   // 64 chunks of 16 steps
    for (int c = 0; c < nch; ++c) {
        if (c + 1 < nch) {
            const float* xr2 = xrow + (size_t)(c + 1) * 16 * DIN;
            #pragma unroll
            for (int i = 0; i < 16; ++i)
                xg[i] = *(const float4*)(xr2 + (size_t)i * DIN);
        }
        #pragma unroll
        for (int i = 0; i < 16; ++i) {
            const int t  = c * 16 + i;
            const int p  = i & 1;
            const int np = p ^ 1;

            // h B-frags (linear ds_read_b128, conflict-free) — first, most urgent
            f16x8 hB[4];
            #pragma unroll
            for (int kt = 0; kt < 4; ++kt)
                hB[kt] = *(const f16x8*)((char*)&hbuf[p][0][0][0] + (kt * 64 + lane) * 16);

            // x B-frags for t+1 (z_next, off critical path)
            int tt = t + 1; if (tt >= T) tt = T - 1;
            const int it = tt & 15;
            char* xb = (char*)&xs[(tt >> 4) & 1][0];
            f16x8 xfA = *(const f16x8*)(xb + ((it * 2 + 0) * 64 + lane) * 16);
            f16x8 xfB = *(const f16x8*)(xb + ((it * 2 + 1) * 64 + lane) * 16);

            // ---- on-path MFMAs: 4 chains (2 mtl x {ya,wa}), depth 4 ----
            f32x4 ya0 = {0.f, 0.f, 0.f, 0.f};
            f32x4 ya1 = {0.f, 0.f, 0.f, 0.f};
            f32x4 wa0 = zc[0];
            f32x4 wa1 = zc[1];
            #pragma unroll
            for (int kt = 0; kt < 4; ++kt) {
                ya0 = MFMA32(AT[0][kt], hB[kt], ya0);
                ya1 = MFMA32(AT[1][kt], hB[kt], ya1);
                wa0 = MFMA32(WT[0][kt], hB[kt], wa0);
                wa1 = MFMA32(WT[1][kt], hB[kt], wa1);
            }

            // ---- epilogue: h += eps*(ya + tanh(wa)); D->B shuffled writes ----
            #pragma unroll
            for (int mtl = 0; mtl < 2; ++mtl) {
                const f32x4 ya = mtl ? ya1 : ya0;
                const f32x4 wa = mtl ? wa1 : wa0;
                f16x4 nh;
                #pragma unroll
                for (int r = 0; r < 4; ++r) {
                    // tanh(a) = 1 - 2*rcp(exp(2a)+1); base runs parallel to exp
                    const float base = fmaf(EPS_C, ya[r], hf[mtl][r]) + EPS_C;
                    const float e2   = __expf(2.0f * wa[r]);
                    const float rc   = __builtin_amdgcn_rcpf(e2 + 1.0f);
                    const float hv   = fmaf(-2.0f * EPS_C, rc, base);
                    hf[mtl][r] = hv;
                    nh[r] = (_Float16)hv;
                }
                char* hwp = (char*)&hbuf[np][w][0][0];
                const int row = (2 * mtl + (q >> 1)) * 16 + lid;
                *(f16x4*)(hwp + row * 16 + (q & 1) * 8) = nh;
            }

            // z(t+1): independent MFMAs fill the pre-barrier window
            f32x4 zn0 = ebv[0], zn1 = ebv[1];
            zn0 = MFMA32(EF[0][0], xfA, zn0);
            zn1 = MFMA32(EF[1][0], xfA, zn1);
            zn0 = MFMA32(EF[0][1], xfB, zn0);
            zn1 = MFMA32(EF[1][1], xfB, zn1);
            zc[0] = zn0;  zc[1] = zn1;

            // staging spread over steps 10..13 (next buf; disjoint from readers)
            if (c + 1 < nch) {
                if (i == 10) STAGE_WRITE_RANGE((c + 1) & 1, 0, 4)
                if (i == 11) STAGE_WRITE_RANGE((c + 1) & 1, 4, 8)
                if (i == 12) STAGE_WRITE_RANGE((c + 1) & 1, 8, 12)
                if (i == 13) STAGE_WRITE_RANGE((c + 1) & 1, 12, 16)
            }
            BAR();   // lgkmcnt(0) + s_barrier; vmcnt stays in flight
        }
    }

    // ---- final: stash h, small output GEMM ----
    #pragma unroll
    for (int mtl = 0; mtl < 2; ++mtl)
        #pragma unroll
        for (int r = 0; r < 4; ++r)
            hfin[lid][(w * 2 + mtl) * 16 + q * 4 + r] = hf[mtl][r];
    __syncthreads();

    if (tid < 16 * COUT) {
        const int r  = tid / COUT;
        const int cc = tid - r * COUT;
        float acc = D_b[cc];
        #pragma unroll 8
        for (int u = 0; u < NU; ++u)
            acc = fmaf(hfin[r][u], D_w[cc * NU + u], acc);
        out[((size_t)g * 16 + r) * COUT + cc] = acc;
    }
}

extern "C" void kernel_launch(void* const* d_in, const int* in_sizes, int n_in,
                              void* d_out, int out_size, void* d_ws, size_t ws_size,
                              hipStream_t stream)
{
    const float* x   = (const float*)d_in[0];
    const float* E_w = (const float*)d_in[1];
    const float* E_b = (const float*)d_in[2];
    const float* B_p = (const float*)d_in[3];
    const float* C_p = (const float*)d_in[4];
    const float* D_w = (const float*)d_in[5];
    const float* D_b = (const float*)d_in[6];
    float* out = (float*)d_out;

    const int B  = out_size / COUT;            // 512
    const int T  = in_sizes[0] / (B * DIN);    // 1024
    const int NB = B / 16;                     // 32 blocks

    rnn_core<<<NB, 256, 0, stream>>>(x, E_w, E_b, B_p, C_p, D_w, D_b, out, T);
}